// Round 8
// baseline (1183.113 us; speedup 1.0000x reference)
//
#include <hip/hip_runtime.h>
#include <hip/hip_bf16.h>

typedef __attribute__((ext_vector_type(4))) float f32x4;
typedef __attribute__((ext_vector_type(8))) short bf16x8;

#define KDIM 512
#define NSLICE 16   // K = 16 slices of 32

// fp32 -> packed 2x bf16 (RNE); compiler emits v_cvt_pk_bf16_f32.
__device__ __forceinline__ unsigned int bfpack(float a, float b) {
  __hip_bfloat162 h = __float22bfloat162_rn(float2{a, b});
  union { __hip_bfloat162 h2; unsigned int u; } c;
  c.h2 = h;
  return c.u;
}

__device__ __forceinline__ bf16x8 cvt8(const f32x4 lo, const f32x4 hi) {
  union { bf16x8 v; unsigned int u[4]; } r;
  r.u[0] = bfpack(lo[0], lo[1]);
  r.u[1] = bfpack(lo[2], lo[3]);
  r.u[2] = bfpack(hi[0], hi[1]);
  r.u[3] = bfpack(hi[2], hi[3]);
  return r.v;
}

// No LDS, no barriers: each wave gathers its MFMA fragments directly from
// global (L1/L2-cached), cvts fp32->bf16 in-register, accumulates.
// Fragment wave-load covers 16 full 128B lines (lane quads {x,x+16,x+32,x+48}
// tile each line) -> fully coalesced at the cache-line level.
__launch_bounds__(256, 3)
__global__ void moe_grouped_gemm(const float* __restrict__ A,
                                 const float* __restrict__ W,
                                 float* __restrict__ C) {
  const int tid  = threadIdx.x;
  const int lane = tid & 63;
  const int wid  = tid >> 6;     // 4 waves, 2x2
  const int wm   = wid >> 1;     // 0..1 (64-row half)
  const int wn   = wid & 1;      // 0..1 (64-col half)

  // XCD map (proven R2): XCD x = expert x; n fastest => 4 consecutive blocks
  // share one A-panel via L2; expert weight panel stays XCD-L2-resident.
  const int b  = blockIdx.x;
  const int L  = (b & 7) * 1024 + (b >> 3);
  const int e  = L >> 10;        // expert
  const int t  = L & 1023;
  const int mt = t >> 2;         // 256 m-tiles (128 rows each)
  const int nt = t & 3;          // 4 n-tiles (128 cols each)

  const size_t mBase = (size_t)e * 32768 + (size_t)mt * 128;
  const int    nBase = nt * 128;

  // fragment lane geometry: row/col = fr, k-window = q8 + slice*32
  const int fr = lane & 15;
  const int q8 = (lane >> 4) << 3;   // 0,8,16,24

  // per-lane base pointers (element units)
  const float* apl = A + (mBase + (size_t)(wm * 64 + fr)) * KDIM + q8;
  const float* bpl = W + ((size_t)e * 512 + nBase + wn * 64 + fr) * KDIM + q8;

  f32x4 acc[4][4];
  #pragma unroll
  for (int i = 0; i < 4; ++i)
    #pragma unroll
    for (int j = 0; j < 4; ++j)
      acc[i][j] = (f32x4){0.f, 0.f, 0.f, 0.f};

  // K loop: per slice, 16 fragment loads (16B/lane) + 32 cvt_pk + 16 MFMA.
  // No barriers anywhere: waves slip independently, loads issue continuously.
  #pragma unroll 2
  for (int s = 0; s < NSLICE; ++s) {
    const int k0 = s * 32;
    bf16x8 afr[4], bfr[4];
    #pragma unroll
    for (int i = 0; i < 4; ++i) {
      const f32x4 alo = *(const f32x4*)(apl + i * 16 * KDIM + k0);
      const f32x4 ahi = *(const f32x4*)(apl + i * 16 * KDIM + k0 + 4);
      const f32x4 blo = *(const f32x4*)(bpl + i * 16 * KDIM + k0);
      const f32x4 bhi = *(const f32x4*)(bpl + i * 16 * KDIM + k0 + 4);
      afr[i] = cvt8(alo, ahi);
      bfr[i] = cvt8(blo, bhi);
    }
    #pragma unroll
    for (int mi = 0; mi < 4; ++mi)
      #pragma unroll
      for (int ni = 0; ni < 4; ++ni)
        acc[mi][ni] = __builtin_amdgcn_mfma_f32_16x16x32_bf16(afr[mi], bfr[ni], acc[mi][ni], 0, 0, 0);
  }

  // ---- epilogue: C/D layout row = (lane>>4)*4 + reg, col = lane&15 ----
  // nontemporal: C is write-once, keep it from evicting A/W in L2/L3.
  #pragma unroll
  for (int mi = 0; mi < 4; ++mi) {
    #pragma unroll
    for (int reg = 0; reg < 4; ++reg) {
      const int r = wm * 64 + mi * 16 + ((lane >> 4) << 2) + reg;
      float* rowp = C + (mBase + r) * 512 + nBase + wn * 64 + (lane & 15);
      #pragma unroll
      for (int ni = 0; ni < 4; ++ni)
        __builtin_nontemporal_store(acc[mi][ni][reg], rowp + ni * 16);
    }
  }
}

extern "C" void kernel_launch(void* const* d_in, const int* in_sizes, int n_in,
                              void* d_out, int out_size, void* d_ws, size_t ws_size,
                              hipStream_t stream) {
  const float* inputs = (const float*)d_in[0];   // [262144, 512] fp32
  const float* weight = (const float*)d_in[1];   // [8, 512, 512] fp32
  float* out = (float*)d_out;                    // [262144, 512] fp32
  (void)d_ws; (void)ws_size; (void)in_sizes; (void)n_in;

  moe_grouped_gemm<<<8192, 256, 0, stream>>>(inputs, weight, out);
}

// Round 9
// 324.197 us; speedup vs baseline: 3.6494x; 3.6494x over previous
//
#include <hip/hip_runtime.h>
#include <hip/hip_bf16.h>

typedef __attribute__((ext_vector_type(4))) float f32x4;
typedef __attribute__((ext_vector_type(8))) short bf16x8;

#define BM 128
#define BN 512
#define BK 32
#define KDIM 512
#define NT 16   // 512/32 K-tiles

// fp32 -> packed 2x bf16 (RNE); compiler emits v_cvt_pk_bf16_f32.
__device__ __forceinline__ unsigned int bfpack(float a, float b) {
  __hip_bfloat162 h = __float22bfloat162_rn(float2{a, b});
  union { __hip_bfloat162 h2; unsigned int u; } c;
  c.h2 = h;
  return c.u;
}

// 16B-granule XOR swizzle — verified 0 conflicts at this exact geometry
// (64B bf16 rows, 8-thr/row uint2 writes, b128 frag reads) in R3/R4/R5.
__device__ __forceinline__ int swz(int row, int col) {
  return col ^ (((row >> 1) & 3) << 3);
}

__launch_bounds__(1024, 1)
__global__ void moe_grouped_gemm(const float* __restrict__ A,
                                 const float* __restrict__ W,
                                 float* __restrict__ C) {
  // Full-N tile: A is read ONCE from HBM (no n-tile re-read -> no L3
  // dependence); W (1 MB/expert) is the only reused operand and stays
  // resident in its XCD's 4 MB L2. LDS: (128+512)*32*2B*2buf = 80 KiB.
  __shared__ ushort As[2][BM][BK];
  __shared__ ushort Ws[2][BN][BK];

  const int tid  = threadIdx.x;
  const int lane = tid & 63;
  const int wid  = tid >> 6;     // 16 waves, 2 x 8
  const int wr   = wid >> 3;     // 0..1 (64-row half)
  const int wc   = wid & 7;      // 0..7 (64-col strip)

  // XCD map: expert = b&7 = XCD; all 32 CUs of an XCD chew the same expert,
  // sharing its 1 MB weight panel in L2.
  const int b  = blockIdx.x;
  const int e  = b & 7;
  const int mt = b >> 3;         // 0..255 m-tiles

  const size_t mBase = (size_t)e * 32768 + (size_t)mt * BM;

  const float* Ap = A + mBase * KDIM;
  const float* Wp = W + (size_t)e * 512 * KDIM;   // full expert panel

  // staging: 8 threads per row, 1 float4 each. A: 128 rows = 1 pass;
  // W: 512 rows = 4 passes.
  const int srow = tid >> 3;            // 0..127
  const int scol = (tid & 7) << 2;      // 0,4,..,28

  // frag geometry
  const int fr    = lane & 15;
  const int kbase = (lane >> 4) << 3;

  f32x4 acc[4][4];
  #pragma unroll
  for (int i = 0; i < 4; ++i)
    #pragma unroll
    for (int j = 0; j < 4; ++j)
      acc[i][j] = (f32x4){0.f, 0.f, 0.f, 0.f};

  // depth-1 staging registers (single set -> fits 128-VGPR/4-wave budget)
  float4 ra;
  float4 rw[4];

#define ISSUE(T)                                                          \
  {                                                                       \
    ra = *(const float4*)(Ap + (size_t)srow * KDIM + (T) * BK + scol);    \
    _Pragma("unroll")                                                     \
    for (int p_ = 0; p_ < 4; ++p_)                                        \
      rw[p_] = *(const float4*)(Wp + (size_t)(p_ * 128 + srow) * KDIM +   \
                                (T) * BK + scol);                         \
  }

#define CVTWRITE(T)                                                       \
  {                                                                       \
    const int buf_ = (T) & 1;                                             \
    const int sc_  = swz(srow, scol);  /* bit7 of row doesn't alter swz */ \
    uint2 pa_;                                                            \
    pa_.x = bfpack(ra.x, ra.y); pa_.y = bfpack(ra.z, ra.w);               \
    *(uint2*)&As[buf_][srow][sc_] = pa_;                                  \
    _Pragma("unroll")                                                     \
    for (int p_ = 0; p_ < 4; ++p_) {                                      \
      uint2 pw_;                                                          \
      pw_.x = bfpack(rw[p_].x, rw[p_].y);                                 \
      pw_.y = bfpack(rw[p_].z, rw[p_].w);                                 \
      *(uint2*)&Ws[buf_][p_ * 128 + srow][sc_] = pw_;                     \
    }                                                                     \
  }

  // ---- prologue: stage tile 0; issue tile 1 ----
  ISSUE(0);
  CVTWRITE(0);
  ISSUE(1);

  // Main loop (R2's best-measured phase order):
  //   sync -> cvt+write t+1 -> issue t+2 -> compute t
  for (int t = 0; t < NT; ++t) {
    __syncthreads();

    if (t + 1 < NT) CVTWRITE(t + 1);
    if (t + 2 < NT) ISSUE(t + 2);
    __builtin_amdgcn_sched_barrier(0);

    // compute tile t from buf t&1
    {
      const int buf = t & 1;
      bf16x8 bf[4], af[4];
      #pragma unroll
      for (int ni = 0; ni < 4; ++ni) {
        const int rrow = wc * 64 + ni * 16 + fr;
        bf[ni] = *(const bf16x8*)&Ws[buf][rrow][swz(rrow, kbase)];
      }
      #pragma unroll
      for (int mi = 0; mi < 4; ++mi) {
        const int arow = wr * 64 + mi * 16 + fr;
        af[mi] = *(const bf16x8*)&As[buf][arow][swz(arow, kbase)];
      }
      #pragma unroll
      for (int mi = 0; mi < 4; ++mi)
        #pragma unroll
        for (int ni = 0; ni < 4; ++ni)
          acc[mi][ni] = __builtin_amdgcn_mfma_f32_16x16x32_bf16(af[mi], bf[ni], acc[mi][ni], 0, 0, 0);
    }
  }

  // ---- epilogue: C/D layout row = (lane>>4)*4 + reg, col = lane&15 ----
  #pragma unroll
  for (int mi = 0; mi < 4; ++mi) {
    #pragma unroll
    for (int reg = 0; reg < 4; ++reg) {
      const int r = wr * 64 + mi * 16 + ((lane >> 4) << 2) + reg;
      float* rowp = C + (mBase + r) * 512 + wc * 64 + (lane & 15);
      #pragma unroll
      for (int ni = 0; ni < 4; ++ni)
        __builtin_nontemporal_store(acc[mi][ni][reg], rowp + ni * 16);
    }
  }
#undef ISSUE
#undef CVTWRITE
}

extern "C" void kernel_launch(void* const* d_in, const int* in_sizes, int n_in,
                              void* d_out, int out_size, void* d_ws, size_t ws_size,
                              hipStream_t stream) {
  const float* inputs = (const float*)d_in[0];   // [262144, 512] fp32
  const float* weight = (const float*)d_in[1];   // [8, 512, 512] fp32
  float* out = (float*)d_out;                    // [262144, 512] fp32
  (void)d_ws; (void)ws_size; (void)in_sizes; (void)n_in;

  moe_grouped_gemm<<<2048, 1024, 0, stream>>>(inputs, weight, out);
}